// Round 6
// baseline (208.053 us; speedup 1.0000x reference)
//
#include <hip/hip_runtime.h>
#include <hip/hip_bf16.h>
#include <hip/hip_fp8.h>
#include <math.h>

typedef __attribute__((ext_vector_type(4))) int   int4v;
typedef __attribute__((ext_vector_type(8))) int   int8v;
typedef __attribute__((ext_vector_type(4))) float f32x4;

#define BM 256
#define BN 128
#define BK 128   // fp8: one 16x16x128 MFMA consumes the whole staged K-slab

union frag_u { int8v v; int4v h[2]; };

// ---------------------------------------------------------------------------
// prep: byte-identical to round 4.
// ---------------------------------------------------------------------------
__global__ __launch_bounds__(256) void prep_kernel(
    const float* __restrict__ X, const float* __restrict__ S,
    unsigned char* __restrict__ Xq, unsigned char* __restrict__ Sq,
    float* __restrict__ x2, float* __restrict__ s2,
    float* __restrict__ rowsum, int M, int R, int Dv)
{
    const int gid  = blockIdx.x * 256 + threadIdx.x;
    const int nthr = gridDim.x * 256;

    for (int i = gid; i < M; i += nthr) rowsum[i] = 0.f;

    const int lane = threadIdx.x & 63;
    const int wid  = gid >> 6;
    const int nw   = nthr >> 6;

    for (int row = wid; row < R; row += nw) {
        const float* rp;
        unsigned char* op;
        float* sq;
        if (row < M) { rp = X + (size_t)row * Dv;       op = Xq + (size_t)row * Dv;       sq = x2 + row; }
        else         { rp = S + (size_t)(row - M) * Dv; op = Sq + (size_t)(row - M) * Dv; sq = s2 + (row - M); }

        float acc = 0.f;
        for (int k = lane * 8; k < Dv; k += 64 * 8) {
            float4 v0 = *(const float4*)(rp + k);
            float4 v1 = *(const float4*)(rp + k + 4);
            acc += v0.x * v0.x + v0.y * v0.y + v0.z * v0.z + v0.w * v0.w;
            acc += v1.x * v1.x + v1.y * v1.y + v1.z * v1.z + v1.w * v1.w;
            int lo = __builtin_amdgcn_cvt_pk_fp8_f32(v0.x, v0.y, 0, false);
            lo     = __builtin_amdgcn_cvt_pk_fp8_f32(v0.z, v0.w, lo, true);
            int hi = __builtin_amdgcn_cvt_pk_fp8_f32(v1.x, v1.y, 0, false);
            hi     = __builtin_amdgcn_cvt_pk_fp8_f32(v1.z, v1.w, hi, true);
            union { int i2[2]; uint2 u; } pk;
            pk.i2[0] = lo; pk.i2[1] = hi;
            *(uint2*)(op + k) = pk.u;
        }
#pragma unroll
        for (int off = 1; off < 64; off <<= 1)
            acc += __shfl_xor(acc, off, 64);
        if (lane == 0) *sq = acc;
    }
}

// ---------------------------------------------------------------------------
// Fused fp8 GEMM + exp-reduce. r5's per-wave shape (64x128, -25% LDS traffic
// per FLOP) WITHOUT r5's occupancy collapse: tile 256x128, 256 threads,
// 4 waves each owning 64 rows x all 128 cols. 48KB single LDS buffer ->
// 3 blocks/CU x 4 waves = 3 waves/SIMD (>= champion's ~2). All champion
// machinery intact: 2 barriers/step, XOR-chunk involution (staging A = 8
// rounds x 32 rows, B = 4 rounds; dest linear-in-lane), direct b128
// fragment reads, same MFMA + epilogue (ni widened to 8).
// Per block-step: stage 48KB, read 96KB for 8.4 MFLOP (champion: 32/64KB
// for 4.2 MFLOP) -> LDS bytes/FLOP x0.75.
// ---------------------------------------------------------------------------
template<int DVC>
__global__ __launch_bounds__(256, 3) void kde_gemm_kernel(
    const unsigned char* __restrict__ Xq,   // [M][D] fp8 e4m3
    const unsigned char* __restrict__ Sq,   // [N][D] fp8 e4m3
    const float* __restrict__ x2,
    const float* __restrict__ s2,
    const float* __restrict__ scale_p,
    float* __restrict__ rowsum,
    int M, int N, int Dv)
{
    const int D = DVC ? DVC : Dv;

    __shared__ char smem[49152];   // As [0,32K) 256x128, Bs [32K,48K) 128x128

    const int tid  = threadIdx.x;   // 0..255
    const int wave = tid >> 6;      // 0..3
    const int lane = tid & 63;
    const int quad = lane >> 4;
    const int l16  = lane & 15;

    const int m0 = blockIdx.x * BM;
    const int n0 = blockIdx.y * BN;
    const int wm = wave * 64;       // wave's 64-row slice; cols = all 128

    const float sc = *scale_p;

    f32x4 acc[4][8] = {};

    // staging: round rd covers 32 rows. Thread t: row-in-round t>>3 (0..31),
    // global 16B-chunk (t&7)^(row&7); LDS dest rd*4096 + t*16 (linear).
    // Read side: logical chunk c of row r sits at physical c^(r&7) — same
    // involution as the 48.2us champion.
    const int srow0 = tid >> 3;                       // 0..31
    const int cg    = (tid & 7) ^ ((tid >> 3) & 7);
    const unsigned char* gA = Xq + (size_t)(m0 + srow0) * D + cg * 16;
    const unsigned char* gB = Sq + (size_t)(n0 + srow0) * D + cg * 16;

    // fragment LDS offsets (k0-invariant; (row&7)==l16&7 since wm,16|8)
    const int e     = l16 & 7;
    const int offLo = ((2 * quad)     ^ e) * 16;
    const int offHi = ((2 * quad + 1) ^ e) * 16;
    int aOff[4], bOff[8];
#pragma unroll
    for (int i = 0; i < 4; ++i)
        aOff[i] = (wm + i * 16 + l16) * 128;          // < 32768
#pragma unroll
    for (int i = 0; i < 8; ++i)
        bOff[i] = 32768 + (i * 16 + l16) * 128;       // < 49152

#pragma unroll
    for (int k0 = 0; k0 < D; k0 += BK) {
        __syncthreads();  // prev iter's ds_reads done before overwrite
#pragma unroll
        for (int rd = 0; rd < 8; ++rd)                // A: 256 rows
            __builtin_amdgcn_global_load_lds(
                (const __attribute__((address_space(1))) void*)(gA + (size_t)rd * 32 * D + k0),
                (__attribute__((address_space(3))) void*)(smem + rd * 4096 + tid * 16),
                16, 0, 0);
#pragma unroll
        for (int rd = 0; rd < 4; ++rd)                // B: 128 rows
            __builtin_amdgcn_global_load_lds(
                (const __attribute__((address_space(1))) void*)(gB + (size_t)rd * 32 * D + k0),
                (__attribute__((address_space(3))) void*)(smem + 32768 + rd * 4096 + tid * 16),
                16, 0, 0);
        __syncthreads();  // staging drained

        frag_u a_frag[4];
#pragma unroll
        for (int mi = 0; mi < 4; ++mi) {
            a_frag[mi].h[0] = *(const int4v*)(smem + aOff[mi] + offLo);
            a_frag[mi].h[1] = *(const int4v*)(smem + aOff[mi] + offHi);
        }
#pragma unroll
        for (int g = 0; g < 2; ++g) {     // B in 2 groups of 4 (VGPR bound)
            frag_u b_frag[4];
#pragma unroll
            for (int nj = 0; nj < 4; ++nj) {
                b_frag[nj].h[0] = *(const int4v*)(smem + bOff[g * 4 + nj] + offLo);
                b_frag[nj].h[1] = *(const int4v*)(smem + bOff[g * 4 + nj] + offHi);
            }
#pragma unroll
            for (int mi = 0; mi < 4; ++mi)
#pragma unroll
                for (int nj = 0; nj < 4; ++nj)
                    acc[mi][g * 4 + nj] = __builtin_amdgcn_mfma_scale_f32_16x16x128_f8f6f4(
                        a_frag[mi].v, b_frag[nj].v, acc[mi][g * 4 + nj],
                        0, 0,                     // cbsz=fp8 e4m3, blgp=fp8 e4m3
                        0, 0x7F7F7F7F,            // A scales: unity E8M0
                        0, 0x7F7F7F7F);           // B scales: unity
        }
    }

    // ---- epilogue. C layout per MFMA: col = l16 (-> n), row = quad*4 + reg.
    __syncthreads();  // all waves done reading As/Bs; reuse LDS
    float* wred = (float*)smem + wave * (64 * 20);  // 5120 B per wave (20KB)

    float s2v[8];
#pragma unroll
    for (int ni = 0; ni < 8; ++ni)
        s2v[ni] = s2[n0 + ni * 16 + l16];

#pragma unroll
    for (int mi = 0; mi < 4; ++mi) {
#pragma unroll
        for (int r = 0; r < 4; ++r) {
            const int rowL = mi * 16 + quad * 4 + r;     // 0..63 within wave
            const float xv = x2[m0 + wm + rowL];
            float sum = 0.f;
#pragma unroll
            for (int ni = 0; ni < 8; ++ni) {
                float d2 = xv + s2v[ni] - 2.0f * acc[mi][ni][r];
                d2 = fmaxf(d2, 0.f);
                sum += __expf(-sc * d2);
            }
            wred[rowL * 20 + l16] = sum;
        }
    }
    __syncthreads();  // order LDS writes before cross-lane reads

    float4 p0 = *(float4*)(wred + lane * 20 + 0);
    float4 p1 = *(float4*)(wred + lane * 20 + 4);
    float4 p2 = *(float4*)(wred + lane * 20 + 8);
    float4 p3 = *(float4*)(wred + lane * 20 + 12);
    float s = (p0.x + p0.y + p0.z + p0.w) + (p1.x + p1.y + p1.z + p1.w)
            + (p2.x + p2.y + p2.z + p2.w) + (p3.x + p3.y + p3.z + p3.w);
    atomicAdd(&rowsum[m0 + wm + lane], s);
}

// ---------------------------------------------------------------------------
__global__ void finalize_kernel(const float* __restrict__ rowsum,
                                const float* __restrict__ scale_p,
                                float* __restrict__ out, int M, int N, int Dv) {
    const int m = blockIdx.x * 256 + threadIdx.x;
    if (m < M) {
        const float sc = *scale_p;
        const float cst = -logf((float)N) + 0.5f * (float)Dv * logf(sc / 3.14159265358979f);
        out[m] = logf(rowsum[m]) + cst;
    }
}

// ---------------------------------------------------------------------------
extern "C" void kernel_launch(void* const* d_in, const int* in_sizes, int n_in,
                              void* d_out, int out_size, void* d_ws, size_t ws_size,
                              hipStream_t stream) {
    const float* X       = (const float*)d_in[0];
    const float* S       = (const float*)d_in[1];
    const float* scale_p = (const float*)d_in[2];
    float* out = (float*)d_out;

    const int M  = out_size;            // 8192
    const int Dv = in_sizes[0] / M;     // 512
    const int N  = in_sizes[1] / Dv;    // 8192

    char* ws = (char*)d_ws;
    unsigned char* Xq = (unsigned char*)ws;
    unsigned char* Sq = (unsigned char*)(ws + (size_t)M * Dv);
    float* x2     = (float*)(ws + (size_t)M * Dv + (size_t)N * Dv);
    float* s2     = x2 + M;
    float* rowsum = s2 + N;

    prep_kernel<<<2048, 256, 0, stream>>>(X, S, Xq, Sq, x2, s2, rowsum, M, M + N, Dv);

    dim3 grid(M / BM, N / BN);
    if (Dv == 512)
        kde_gemm_kernel<512><<<grid, 256, 0, stream>>>(Xq, Sq, x2, s2, scale_p, rowsum, M, N, Dv);
    else
        kde_gemm_kernel<0><<<grid, 256, 0, stream>>>(Xq, Sq, x2, s2, scale_p, rowsum, M, N, Dv);

    finalize_kernel<<<(M + 255) / 256, 256, 0, stream>>>(rowsum, scale_p, out, M, N, Dv);
}

// Round 7
// 120.686 us; speedup vs baseline: 1.7239x; 1.7239x over previous
//
#include <hip/hip_runtime.h>
#include <hip/hip_bf16.h>
#include <hip/hip_fp8.h>
#include <math.h>

typedef __attribute__((ext_vector_type(4))) int   int4v;
typedef __attribute__((ext_vector_type(8))) int   int8v;
typedef __attribute__((ext_vector_type(4))) float f32x4;

#define BM 256
#define BN 128
#define BK 128   // fp8: one 16x16x128 MFMA consumes the whole staged K-slab

union frag_u { int8v v; int4v h[2]; };

// ---------------------------------------------------------------------------
// prep: byte-identical to round 4.
// ---------------------------------------------------------------------------
__global__ __launch_bounds__(256) void prep_kernel(
    const float* __restrict__ X, const float* __restrict__ S,
    unsigned char* __restrict__ Xq, unsigned char* __restrict__ Sq,
    float* __restrict__ x2, float* __restrict__ s2,
    float* __restrict__ rowsum, int M, int R, int Dv)
{
    const int gid  = blockIdx.x * 256 + threadIdx.x;
    const int nthr = gridDim.x * 256;

    for (int i = gid; i < M; i += nthr) rowsum[i] = 0.f;

    const int lane = threadIdx.x & 63;
    const int wid  = gid >> 6;
    const int nw   = nthr >> 6;

    for (int row = wid; row < R; row += nw) {
        const float* rp;
        unsigned char* op;
        float* sq;
        if (row < M) { rp = X + (size_t)row * Dv;       op = Xq + (size_t)row * Dv;       sq = x2 + row; }
        else         { rp = S + (size_t)(row - M) * Dv; op = Sq + (size_t)(row - M) * Dv; sq = s2 + (row - M); }

        float acc = 0.f;
        for (int k = lane * 8; k < Dv; k += 64 * 8) {
            float4 v0 = *(const float4*)(rp + k);
            float4 v1 = *(const float4*)(rp + k + 4);
            acc += v0.x * v0.x + v0.y * v0.y + v0.z * v0.z + v0.w * v0.w;
            acc += v1.x * v1.x + v1.y * v1.y + v1.z * v1.z + v1.w * v1.w;
            int lo = __builtin_amdgcn_cvt_pk_fp8_f32(v0.x, v0.y, 0, false);
            lo     = __builtin_amdgcn_cvt_pk_fp8_f32(v0.z, v0.w, lo, true);
            int hi = __builtin_amdgcn_cvt_pk_fp8_f32(v1.x, v1.y, 0, false);
            hi     = __builtin_amdgcn_cvt_pk_fp8_f32(v1.z, v1.w, hi, true);
            union { int i2[2]; uint2 u; } pk;
            pk.i2[0] = lo; pk.i2[1] = hi;
            *(uint2*)(op + k) = pk.u;
        }
#pragma unroll
        for (int off = 1; off < 64; off <<= 1)
            acc += __shfl_xor(acc, off, 64);
        if (lane == 0) *sq = acc;
    }
}

// ---------------------------------------------------------------------------
// Fused fp8 GEMM + exp-reduce. IDENTICAL to round 6 except
// __launch_bounds__(256,2): r6's (256,3) capped VGPR at ~168, spilling the
// 128-reg accumulator to scratch (WRITE_SIZE 4MB->400MB, VGPR=84, MfmaUtil
// 8.7%). With min-waves=2 the allocator gets 256 VGPRs -> no spill; LDS
// 48KB + VGPR both give 2 blocks/CU = 8 waves/CU = champion's measured
// occupancy, so this is the first OCCUPANCY-CONTROLLED test of the -25%
// LDS-traffic shape (4 waves x 64x128 on a 256x128 tile).
// ---------------------------------------------------------------------------
template<int DVC>
__global__ __launch_bounds__(256, 2) void kde_gemm_kernel(
    const unsigned char* __restrict__ Xq,   // [M][D] fp8 e4m3
    const unsigned char* __restrict__ Sq,   // [N][D] fp8 e4m3
    const float* __restrict__ x2,
    const float* __restrict__ s2,
    const float* __restrict__ scale_p,
    float* __restrict__ rowsum,
    int M, int N, int Dv)
{
    const int D = DVC ? DVC : Dv;

    __shared__ char smem[49152];   // As [0,32K) 256x128, Bs [32K,48K) 128x128

    const int tid  = threadIdx.x;   // 0..255
    const int wave = tid >> 6;      // 0..3
    const int lane = tid & 63;
    const int quad = lane >> 4;
    const int l16  = lane & 15;

    const int m0 = blockIdx.x * BM;
    const int n0 = blockIdx.y * BN;
    const int wm = wave * 64;       // wave's 64-row slice; cols = all 128

    const float sc = *scale_p;

    f32x4 acc[4][8] = {};

    // staging: round rd covers 32 rows. Thread t: row-in-round t>>3 (0..31),
    // global 16B-chunk (t&7)^(row&7); LDS dest rd*4096 + t*16 (linear).
    // Read side: logical chunk c of row r sits at physical c^(r&7).
    const int srow0 = tid >> 3;                       // 0..31
    const int cg    = (tid & 7) ^ ((tid >> 3) & 7);
    const unsigned char* gA = Xq + (size_t)(m0 + srow0) * D + cg * 16;
    const unsigned char* gB = Sq + (size_t)(n0 + srow0) * D + cg * 16;

    // fragment LDS offsets (k0-invariant; (row&7)==l16&7 since wm,16|8)
    const int e     = l16 & 7;
    const int offLo = ((2 * quad)     ^ e) * 16;
    const int offHi = ((2 * quad + 1) ^ e) * 16;
    int aOff[4], bOff[8];
#pragma unroll
    for (int i = 0; i < 4; ++i)
        aOff[i] = (wm + i * 16 + l16) * 128;          // < 32768
#pragma unroll
    for (int i = 0; i < 8; ++i)
        bOff[i] = 32768 + (i * 16 + l16) * 128;       // < 49152

#pragma unroll
    for (int k0 = 0; k0 < D; k0 += BK) {
        __syncthreads();  // prev iter's ds_reads done before overwrite
#pragma unroll
        for (int rd = 0; rd < 8; ++rd)                // A: 256 rows
            __builtin_amdgcn_global_load_lds(
                (const __attribute__((address_space(1))) void*)(gA + (size_t)rd * 32 * D + k0),
                (__attribute__((address_space(3))) void*)(smem + rd * 4096 + tid * 16),
                16, 0, 0);
#pragma unroll
        for (int rd = 0; rd < 4; ++rd)                // B: 128 rows
            __builtin_amdgcn_global_load_lds(
                (const __attribute__((address_space(1))) void*)(gB + (size_t)rd * 32 * D + k0),
                (__attribute__((address_space(3))) void*)(smem + 32768 + rd * 4096 + tid * 16),
                16, 0, 0);
        __syncthreads();  // staging drained

        frag_u a_frag[4];
#pragma unroll
        for (int mi = 0; mi < 4; ++mi) {
            a_frag[mi].h[0] = *(const int4v*)(smem + aOff[mi] + offLo);
            a_frag[mi].h[1] = *(const int4v*)(smem + aOff[mi] + offHi);
        }
#pragma unroll
        for (int g = 0; g < 2; ++g) {     // B in 2 groups of 4 (VGPR bound)
            frag_u b_frag[4];
#pragma unroll
            for (int nj = 0; nj < 4; ++nj) {
                b_frag[nj].h[0] = *(const int4v*)(smem + bOff[g * 4 + nj] + offLo);
                b_frag[nj].h[1] = *(const int4v*)(smem + bOff[g * 4 + nj] + offHi);
            }
#pragma unroll
            for (int mi = 0; mi < 4; ++mi)
#pragma unroll
                for (int nj = 0; nj < 4; ++nj)
                    acc[mi][g * 4 + nj] = __builtin_amdgcn_mfma_scale_f32_16x16x128_f8f6f4(
                        a_frag[mi].v, b_frag[nj].v, acc[mi][g * 4 + nj],
                        0, 0,                     // cbsz=fp8 e4m3, blgp=fp8 e4m3
                        0, 0x7F7F7F7F,            // A scales: unity E8M0
                        0, 0x7F7F7F7F);           // B scales: unity
        }
    }

    // ---- epilogue. C layout per MFMA: col = l16 (-> n), row = quad*4 + reg.
    __syncthreads();  // all waves done reading As/Bs; reuse LDS
    float* wred = (float*)smem + wave * (64 * 20);  // 5120 B per wave (20KB)

    float s2v[8];
#pragma unroll
    for (int ni = 0; ni < 8; ++ni)
        s2v[ni] = s2[n0 + ni * 16 + l16];

#pragma unroll
    for (int mi = 0; mi < 4; ++mi) {
#pragma unroll
        for (int r = 0; r < 4; ++r) {
            const int rowL = mi * 16 + quad * 4 + r;     // 0..63 within wave
            const float xv = x2[m0 + wm + rowL];
            float sum = 0.f;
#pragma unroll
            for (int ni = 0; ni < 8; ++ni) {
                float d2 = xv + s2v[ni] - 2.0f * acc[mi][ni][r];
                d2 = fmaxf(d2, 0.f);
                sum += __expf(-sc * d2);
            }
            wred[rowL * 20 + l16] = sum;
        }
    }
    __syncthreads();  // order LDS writes before cross-lane reads

    float4 p0 = *(float4*)(wred + lane * 20 + 0);
    float4 p1 = *(float4*)(wred + lane * 20 + 4);
    float4 p2 = *(float4*)(wred + lane * 20 + 8);
    float4 p3 = *(float4*)(wred + lane * 20 + 12);
    float s = (p0.x + p0.y + p0.z + p0.w) + (p1.x + p1.y + p1.z + p1.w)
            + (p2.x + p2.y + p2.z + p2.w) + (p3.x + p3.y + p3.z + p3.w);
    atomicAdd(&rowsum[m0 + wm + lane], s);
}

// ---------------------------------------------------------------------------
__global__ void finalize_kernel(const float* __restrict__ rowsum,
                                const float* __restrict__ scale_p,
                                float* __restrict__ out, int M, int N, int Dv) {
    const int m = blockIdx.x * 256 + threadIdx.x;
    if (m < M) {
        const float sc = *scale_p;
        const float cst = -logf((float)N) + 0.5f * (float)Dv * logf(sc / 3.14159265358979f);
        out[m] = logf(rowsum[m]) + cst;
    }
}

// ---------------------------------------------------------------------------
extern "C" void kernel_launch(void* const* d_in, const int* in_sizes, int n_in,
                              void* d_out, int out_size, void* d_ws, size_t ws_size,
                              hipStream_t stream) {
    const float* X       = (const float*)d_in[0];
    const float* S       = (const float*)d_in[1];
    const float* scale_p = (const float*)d_in[2];
    float* out = (float*)d_out;

    const int M  = out_size;            // 8192
    const int Dv = in_sizes[0] / M;     // 512
    const int N  = in_sizes[1] / Dv;    // 8192

    char* ws = (char*)d_ws;
    unsigned char* Xq = (unsigned char*)ws;
    unsigned char* Sq = (unsigned char*)(ws + (size_t)M * Dv);
    float* x2     = (float*)(ws + (size_t)M * Dv + (size_t)N * Dv);
    float* s2     = x2 + M;
    float* rowsum = s2 + N;

    prep_kernel<<<2048, 256, 0, stream>>>(X, S, Xq, Sq, x2, s2, rowsum, M, M + N, Dv);

    dim3 grid(M / BM, N / BN);
    if (Dv == 512)
        kde_gemm_kernel<512><<<grid, 256, 0, stream>>>(Xq, Sq, x2, s2, scale_p, rowsum, M, N, Dv);
    else
        kde_gemm_kernel<0><<<grid, 256, 0, stream>>>(Xq, Sq, x2, s2, scale_p, rowsum, M, N, Dv);

    finalize_kernel<<<(M + 255) / 256, 256, 0, stream>>>(rowsum, scale_p, out, M, N, Dv);
}